// Round 1
// baseline (27.399 us; speedup 1.0000x reference)
//
#include <hip/hip_runtime.h>

// Problem constants (match reference: B=8192, S=7, C=30)
#define YB     8192
#define YS     7
#define YC     30
#define NCELLS (YB * YS * YS)      // 401408
#define CPT    256                 // cells per block (one per thread)
#define NBLK   (NCELLS / CPT)      // 1568, divides exactly
#define BLOCK  256

__device__ __forceinline__ float iou_quirk(float cx1, float cy1, float w1, float h1,
                                           float cx2, float cy2, float w2, float h2) {
    // Faithful replica of reference _iou, including inter/area1 + area2 - inter quirk.
    float area1 = w1 * h1;
    float area2 = w2 * h2;
    float max_left   = fmaxf(cx1 - w1 * 0.5f, cx2 - w2 * 0.5f);
    float min_right  = fminf(cx1 + w1 * 0.5f, cx2 + w2 * 0.5f);
    float max_top    = fmaxf(cy1 - h1 * 0.5f, cy2 - h2 * 0.5f);
    float min_bottom = fminf(cy1 + h1 * 0.5f, cy2 + h2 * 0.5f);
    float inter = (min_right - max_left) * (min_bottom - max_top);
    bool overlap = (max_left < min_right) && (max_top < min_bottom);
    return overlap ? (inter / area1 + area2 - inter) : 0.0f;
}

__global__ __launch_bounds__(BLOCK) void yolo_partial_kernel(const float* __restrict__ preds,
                                                             const float* __restrict__ labels,
                                                             float* __restrict__ partial) {
    __shared__ float sp[CPT * YC];   // 30720 B
    __shared__ float sl[CPT * YC];   // 30720 B
    __shared__ float wsum[BLOCK / 64];

    const int tid = threadIdx.x;
    const long base = (long)blockIdx.x * (CPT * YC);

    // Coalesced float4 staging: tile base is 16B-aligned (CPT*YC*4 = 30720).
    const float4* gp = (const float4*)(preds + base);
    const float4* gl = (const float4*)(labels + base);
    float4* sp4 = (float4*)sp;
    float4* sl4 = (float4*)sl;
    const int NV = CPT * YC / 4;     // 1920 float4 per input tile
    for (int i = tid; i < NV; i += BLOCK) {
        sp4[i] = gp[i];
        sl4[i] = gl[i];
    }
    __syncthreads();

    const float* p = sp + tid * YC;
    const float* l = sl + tid * YC;

    float p0 = p[0], p1 = p[1], p2 = p[2], p3 = p[3], p4 = p[4];
    float p5 = p[5], p6 = p[6], p7 = p[7], p8 = p[8], p9 = p[9];
    float l0 = l[0], l1 = l[1], l2 = l[2], l3 = l[3], l4 = l[4];
    float l5 = l[5], l6 = l[6], l7 = l[7], l8 = l[8];

    float iou1 = iou_quirk(p0, p1, p2, p3, l0, l1, l2, l3);
    float iou2 = iou_quirk(p5, p6, p7, p8, l5, l6, l7, l8);
    bool resp1 = iou1 > iou2;

    float dx1 = p0 - l0, dy1 = p1 - l1;
    float xy1 = dx1 * dx1 + dy1 * dy1;
    float dx2 = p5 - l5, dy2 = p6 - l6;
    float xy2 = dx2 * dx2 + dy2 * dy2;

    float sw1 = sqrtf(p2) - sqrtf(l2), sh1 = sqrtf(p3) - sqrtf(l3);
    float wh1 = sw1 * sw1 + sh1 * sh1;
    float sw2 = sqrtf(p7) - sqrtf(l7), sh2 = sqrtf(p8) - sqrtf(l8);
    float wh2 = sw2 * sw2 + sh2 * sh2;

    float d1 = p4 - iou1, d2 = p9 - iou2;
    float e1 = d1 * d1, e2 = d2 * d2;

    float loss_xy = 5.0f * (resp1 ? xy1 : xy2);
    float loss_wh = resp1 ? wh1 : wh2;
    float loss_obj = resp1 ? e1 : e2;
    float loss_noobj_objcell = 0.5f * (resp1 ? e2 : e1);

    float loss_cls = 0.0f;
    #pragma unroll
    for (int c = 10; c < YC; ++c) {
        float d = p[c] - l[c];
        loss_cls += d * d;
    }

    float obj_cell = loss_xy + loss_wh + loss_obj + loss_noobj_objcell + loss_cls;
    float noobj_cell = 0.5f * (p4 * p4 + p9 * p9);

    // labels[...,4] is exactly 0.0 or 1.0
    float v = (l4 == 1.0f) ? obj_cell : noobj_cell;

    // Deterministic block reduction: wave64 shuffle tree, then cross-wave via LDS.
    for (int off = 32; off > 0; off >>= 1) v += __shfl_down(v, off);
    const int lane = tid & 63, wid = tid >> 6;
    if (lane == 0) wsum[wid] = v;
    __syncthreads();
    if (tid == 0) partial[blockIdx.x] = wsum[0] + wsum[1] + wsum[2] + wsum[3];
}

__global__ __launch_bounds__(BLOCK) void yolo_final_kernel(const float* __restrict__ partial,
                                                           float* __restrict__ out) {
    __shared__ double w[BLOCK / 64];
    double s = 0.0;
    for (int i = threadIdx.x; i < NBLK; i += BLOCK) s += (double)partial[i];
    for (int off = 32; off > 0; off >>= 1) s += __shfl_down(s, off);
    const int lane = threadIdx.x & 63, wid = threadIdx.x >> 6;
    if (lane == 0) w[wid] = s;
    __syncthreads();
    if (threadIdx.x == 0) out[0] = (float)((w[0] + w[1] + w[2] + w[3]) / (double)YB);
}

extern "C" void kernel_launch(void* const* d_in, const int* in_sizes, int n_in,
                              void* d_out, int out_size, void* d_ws, size_t ws_size,
                              hipStream_t stream) {
    const float* preds  = (const float*)d_in[0];
    const float* labels = (const float*)d_in[1];
    float* out = (float*)d_out;
    float* partial = (float*)d_ws;   // needs NBLK*4 = 6272 bytes

    yolo_partial_kernel<<<NBLK, BLOCK, 0, stream>>>(preds, labels, partial);
    yolo_final_kernel<<<1, BLOCK, 0, stream>>>(partial, out);
}

// Round 2
// 25.176 us; speedup vs baseline: 1.0883x; 1.0883x over previous
//
#include <hip/hip_runtime.h>

// Problem constants (match reference: B=8192, S=7, C=30)
#define YB     8192
#define YS     7
#define YC     30
#define NCELLS (YB * YS * YS)      // 401408
#define CPT    128                 // cells per block
#define NBLK   (NCELLS / CPT)      // 3136, divides exactly
#define BLOCK  256

__device__ __forceinline__ float iou_quirk(float cx1, float cy1, float w1, float h1,
                                           float cx2, float cy2, float w2, float h2) {
    // Faithful replica of reference _iou, including inter/area1 + area2 - inter quirk.
    float area1 = w1 * h1;
    float area2 = w2 * h2;
    float max_left   = fmaxf(cx1 - w1 * 0.5f, cx2 - w2 * 0.5f);
    float min_right  = fminf(cx1 + w1 * 0.5f, cx2 + w2 * 0.5f);
    float max_top    = fmaxf(cy1 - h1 * 0.5f, cy2 - h2 * 0.5f);
    float min_bottom = fminf(cy1 + h1 * 0.5f, cy2 + h2 * 0.5f);
    float inter = (min_right - max_left) * (min_bottom - max_top);
    bool overlap = (max_left < min_right) && (max_top < min_bottom);
    return overlap ? (inter / area1 + area2 - inter) : 0.0f;
}

__global__ __launch_bounds__(BLOCK) void yolo_partial_kernel(const float* __restrict__ preds,
                                                             const float* __restrict__ labels,
                                                             float* __restrict__ partial) {
    __shared__ float sp[CPT * YC];   // 15360 B
    __shared__ float sl[CPT * YC];   // 15360 B
    __shared__ float wsum[2];

    const int tid = threadIdx.x;
    const long base = (long)blockIdx.x * (CPT * YC);

    // Coalesced float4 staging: tile base is 16B-aligned (CPT*YC*4 = 15360).
    const float4* gp = (const float4*)(preds + base);
    const float4* gl = (const float4*)(labels + base);
    float4* sp4 = (float4*)sp;
    float4* sl4 = (float4*)sl;
    const int NV = CPT * YC / 4;     // 960 float4 per input tile

#if defined(__has_builtin) && __has_builtin(__builtin_amdgcn_global_load_lds)
    typedef const __attribute__((address_space(1))) void* as1_t;
    typedef __attribute__((address_space(3))) void* as3_t;
    for (int i = tid; i < NV; i += BLOCK)
        __builtin_amdgcn_global_load_lds((as1_t)(gp + i), (as3_t)(sp4 + i), 16, 0, 0);
    for (int i = tid; i < NV; i += BLOCK)
        __builtin_amdgcn_global_load_lds((as1_t)(gl + i), (as3_t)(sl4 + i), 16, 0, 0);
#else
    for (int i = tid; i < NV; i += BLOCK) {
        sp4[i] = gp[i];
        sl4[i] = gl[i];
    }
#endif
    __syncthreads();   // compiler emits s_waitcnt vmcnt(0) before s_barrier

    float v = 0.0f;
    if (tid < CPT) {
        // Vector LDS reads: cell base = tid*120 B, 8B-aligned -> float2 ok.
        const float2* p2 = (const float2*)(sp + tid * YC);
        const float2* l2 = (const float2*)(sl + tid * YC);
        float pv[YC], lv[YC];
        #pragma unroll
        for (int i = 0; i < YC / 2; ++i) {
            float2 a = p2[i]; pv[2 * i] = a.x; pv[2 * i + 1] = a.y;
            float2 b = l2[i]; lv[2 * i] = b.x; lv[2 * i + 1] = b.y;
        }

        float iou1 = iou_quirk(pv[0], pv[1], pv[2], pv[3], lv[0], lv[1], lv[2], lv[3]);
        float iou2 = iou_quirk(pv[5], pv[6], pv[7], pv[8], lv[5], lv[6], lv[7], lv[8]);
        bool resp1 = iou1 > iou2;

        float dx1 = pv[0] - lv[0], dy1 = pv[1] - lv[1];
        float xy1 = dx1 * dx1 + dy1 * dy1;
        float dx2 = pv[5] - lv[5], dy2 = pv[6] - lv[6];
        float xy2 = dx2 * dx2 + dy2 * dy2;

        float sw1 = sqrtf(pv[2]) - sqrtf(lv[2]), sh1 = sqrtf(pv[3]) - sqrtf(lv[3]);
        float wh1 = sw1 * sw1 + sh1 * sh1;
        float sw2 = sqrtf(pv[7]) - sqrtf(lv[7]), sh2 = sqrtf(pv[8]) - sqrtf(lv[8]);
        float wh2 = sw2 * sw2 + sh2 * sh2;

        float d1 = pv[4] - iou1, d2 = pv[9] - iou2;
        float e1 = d1 * d1, e2 = d2 * d2;

        float loss_xy = 5.0f * (resp1 ? xy1 : xy2);
        float loss_wh = resp1 ? wh1 : wh2;
        float loss_obj = resp1 ? e1 : e2;
        float loss_noobj_objcell = 0.5f * (resp1 ? e2 : e1);

        float loss_cls = 0.0f;
        #pragma unroll
        for (int c = 10; c < YC; ++c) {
            float d = pv[c] - lv[c];
            loss_cls += d * d;
        }

        float obj_cell = loss_xy + loss_wh + loss_obj + loss_noobj_objcell + loss_cls;
        float noobj_cell = 0.5f * (pv[4] * pv[4] + pv[9] * pv[9]);

        // labels[...,4] is exactly 0.0 or 1.0
        v = (lv[4] == 1.0f) ? obj_cell : noobj_cell;
    }

    // Deterministic reduction over waves 0,1 (tid < 128).
    if (tid < CPT) {
        for (int off = 32; off > 0; off >>= 1) v += __shfl_down(v, off);
        if ((tid & 63) == 0) wsum[tid >> 6] = v;
    }
    __syncthreads();
    if (tid == 0) partial[blockIdx.x] = wsum[0] + wsum[1];
}

__global__ __launch_bounds__(BLOCK) void yolo_final_kernel(const float* __restrict__ partial,
                                                           float* __restrict__ out) {
    __shared__ double w[BLOCK / 64];
    double s = 0.0;
    for (int i = threadIdx.x; i < NBLK; i += BLOCK) s += (double)partial[i];
    for (int off = 32; off > 0; off >>= 1) s += __shfl_down(s, off);
    const int lane = threadIdx.x & 63, wid = threadIdx.x >> 6;
    if (lane == 0) w[wid] = s;
    __syncthreads();
    if (threadIdx.x == 0) out[0] = (float)((w[0] + w[1] + w[2] + w[3]) / (double)YB);
}

extern "C" void kernel_launch(void* const* d_in, const int* in_sizes, int n_in,
                              void* d_out, int out_size, void* d_ws, size_t ws_size,
                              hipStream_t stream) {
    const float* preds  = (const float*)d_in[0];
    const float* labels = (const float*)d_in[1];
    float* out = (float*)d_out;
    float* partial = (float*)d_ws;   // needs NBLK*4 = 12544 bytes

    yolo_partial_kernel<<<NBLK, BLOCK, 0, stream>>>(preds, labels, partial);
    yolo_final_kernel<<<1, BLOCK, 0, stream>>>(partial, out);
}